// Round 5
// baseline (6042.472 us; speedup 1.0000x reference)
//
#include <hip/hip_runtime.h>
#include <math.h>
#include <stdint.h>

#define NPTS 8192
#define FIN 512
#define FHID 512
#define FOUT 256
#define NCLU 10
#define KNEI 10
#define GAMMA_F 2.0f

// ---------------- sum of squares per row ----------------
__global__ void k_sumsq(const float* __restrict__ x, float* __restrict__ sq) {
    int row = blockIdx.x;
    const float* xr = x + (size_t)row * FIN;
    float s = 0.f;
    for (int k = threadIdx.x; k < FIN; k += 256) s += xr[k] * xr[k];
    __shared__ float red[256];
    red[threadIdx.x] = s; __syncthreads();
    for (int off = 128; off > 0; off >>= 1) {
        if (threadIdx.x < off) red[threadIdx.x] += red[threadIdx.x + off];
        __syncthreads();
    }
    if (threadIdx.x == 0) sq[row] = red[0];
}

// ---------------- fused gram + exp + per-row top-10 ----------------
// block: 256 threads, owns GR_ROWS=16 rows, loops over all 8192 cols in tiles of 512.
#define GR_ROWS 16
#define GR_BN 512
#define GR_KT 16
#define GR_TILES (NPTS / GR_BN)   // 16
#define GR_KCH (FIN / GR_KT)      // 32

__global__ __launch_bounds__(256, 2) void k_gram_topk(
    const float* __restrict__ x, const float* __restrict__ sq, int* __restrict__ topidx)
{
    __shared__ float Al[GR_ROWS][GR_KT + 1];
    __shared__ float Bl[GR_BN][GR_KT + 1];
    __shared__ float Sl[GR_ROWS][GR_BN + 1];
    __shared__ float tval[GR_ROWS][KNEI];
    __shared__ int   tidxs[GR_ROWS][KNEI];

    const int tid = threadIdx.x;
    const int r0 = blockIdx.x * GR_ROWS;

    if (tid < GR_ROWS * KNEI) {
        tval[tid / KNEI][tid % KNEI] = -INFINITY;
        tidxs[tid / KNEI][tid % KNEI] = 0x7fffffff;
    }
    __syncthreads();

    for (int t = 0; t < GR_TILES; ++t) {
        float acc0[GR_ROWS], acc1[GR_ROWS];
        #pragma unroll
        for (int r = 0; r < GR_ROWS; ++r) { acc0[r] = 0.f; acc1[r] = 0.f; }

        for (int kc = 0; kc < GR_KCH; ++kc) {
            {   // A tile: 16x16
                int r = tid >> 4, k = tid & 15;
                Al[r][k] = x[(size_t)(r0 + r) * FIN + kc * GR_KT + k];
            }
            #pragma unroll
            for (int m = 0; m < 32; ++m) {  // B tile: 512x16
                int e = m * 256 + tid;
                int br = e >> 4, bk = e & 15;
                Bl[br][bk] = x[(size_t)(t * GR_BN + br) * FIN + kc * GR_KT + bk];
            }
            __syncthreads();
            #pragma unroll
            for (int k = 0; k < GR_KT; ++k) {
                float b0 = Bl[tid][k];
                float b1 = Bl[tid + 256][k];
                #pragma unroll
                for (int r = 0; r < GR_ROWS; ++r) {
                    float a = Al[r][k];
                    acc0[r] = fmaf(a, b0, acc0[r]);
                    acc1[r] = fmaf(a, b1, acc1[r]);
                }
            }
            __syncthreads();
        }

        // epilogue: S = exp(-d2/GAMMA), diag = -inf
        int j0 = t * GR_BN + tid;
        int j1 = j0 + 256;
        float sj0 = sq[j0], sj1 = sq[j1];
        #pragma unroll
        for (int r = 0; r < GR_ROWS; ++r) {
            int gi = r0 + r;
            float si = sq[gi];
            float d0 = si + sj0 - 2.f * acc0[r];
            float d1 = si + sj1 - 2.f * acc1[r];
            float s0 = (j0 == gi) ? -INFINITY : expf(-d0 / GAMMA_F);
            float s1 = (j1 == gi) ? -INFINITY : expf(-d1 / GAMMA_F);
            Sl[r][tid] = s0;
            Sl[r][tid + 256] = s1;
        }
        __syncthreads();

        // top-10 update, strict order (val desc, idx asc). wave w owns rows 4w..4w+3.
        int wv = tid >> 6, lane = tid & 63;
        for (int q = 0; q < 4; ++q) {
            int r = wv * 4 + q;
            for (int base = 0; base < GR_BN; base += 64) {
                float v = Sl[r][base + lane];
                int gj = t * GR_BN + base + lane;
                float rv9 = tval[r][KNEI - 1];
                int ri9 = tidxs[r][KNEI - 1];
                unsigned long long bal = __ballot(v > rv9 || (v == rv9 && gj < ri9));
                if (lane == 0 && bal) {
                    while (bal) {
                        int l = __ffsll((unsigned long long)bal) - 1;
                        bal &= bal - 1;
                        float cv = Sl[r][base + l];
                        int cj = t * GR_BN + base + l;
                        float a9 = tval[r][KNEI - 1];
                        int i9 = tidxs[r][KNEI - 1];
                        if (cv > a9 || (cv == a9 && cj < i9)) {
                            int pp = KNEI - 1;
                            tval[r][pp] = cv; tidxs[r][pp] = cj;
                            while (pp > 0) {
                                float pv = tval[r][pp - 1]; int pi = tidxs[r][pp - 1];
                                if (cv > pv || (cv == pv && cj < pi)) {
                                    tval[r][pp] = pv; tidxs[r][pp] = pi;
                                    tval[r][pp - 1] = cv; tidxs[r][pp - 1] = cj;
                                    --pp;
                                } else break;
                            }
                        }
                    }
                }
            }
        }
        __syncthreads();
    }

    if (tid < GR_ROWS * KNEI) {
        int r = tid / KNEI, m = tid % KNEI;
        topidx[(size_t)(r0 + r) * KNEI + m] = tidxs[r][m];
    }
}

// ---------------- build symmetric adjacency bitmask ----------------
__global__ void k_set_edges(const int* __restrict__ topidx, unsigned int* __restrict__ mask) {
    int t = blockIdx.x * 256 + threadIdx.x;
    if (t >= NPTS * KNEI) return;
    int i = t / KNEI;
    int j = topidx[t];
    atomicOr(&mask[(size_t)i * (NPTS / 32) + (j >> 5)], 1u << (j & 31));
    atomicOr(&mask[(size_t)j * (NPTS / 32) + (i >> 5)], 1u << (i & 31));
}

// ---------------- degree, inv, total edges ----------------
__global__ void k_degree(const unsigned int* __restrict__ mask, float* __restrict__ degf,
                         float* __restrict__ inv, float* __restrict__ Esum) {
    int i = blockIdx.x, lane = threadIdx.x;  // 64 threads
    int c = 0;
    for (int w = lane; w < NPTS / 32; w += 64) c += __popc(mask[(size_t)i * (NPTS / 32) + w]);
    for (int off = 32; off > 0; off >>= 1) c += __shfl_xor(c, off);
    if (lane == 0) {
        float d = (float)c;
        degf[i] = d;
        inv[i] = (c > 0) ? 1.0f / d : 0.0f;
        atomicAdd(Esum, d);
    }
}

// ---------------- generic f32 GEMM: C[M,Nd] = A[M,Kd] @ B[Kd,Nd] ----------------
__global__ __launch_bounds__(256) void k_gemm(const float* __restrict__ A, const float* __restrict__ B,
                                              float* __restrict__ C, int M, int Kd, int Nd) {
    __shared__ float Al[64][17];
    __shared__ float Bl[16][65];
    int tid = threadIdx.x;
    int bx = blockIdx.x, by = blockIdx.y;
    int tx = tid & 15, ty = tid >> 4;
    float acc[4][4];
    #pragma unroll
    for (int i = 0; i < 4; i++)
        #pragma unroll
        for (int j = 0; j < 4; j++) acc[i][j] = 0.f;

    for (int kt = 0; kt < Kd; kt += 16) {
        #pragma unroll
        for (int l = 0; l < 4; l++) {
            int e = tid + l * 256;
            int r = e >> 4, k = e & 15;
            Al[r][k] = A[(size_t)(by * 64 + r) * Kd + kt + k];
        }
        #pragma unroll
        for (int l = 0; l < 4; l++) {
            int e = tid + l * 256;
            int r = e >> 6, n = e & 63;
            Bl[r][n] = B[(size_t)(kt + r) * Nd + bx * 64 + n];
        }
        __syncthreads();
        #pragma unroll
        for (int k = 0; k < 16; k++) {
            float a[4], b[4];
            #pragma unroll
            for (int i = 0; i < 4; i++) a[i] = Al[ty * 4 + i][k];
            #pragma unroll
            for (int j = 0; j < 4; j++) b[j] = Bl[k][tx * 4 + j];
            #pragma unroll
            for (int i = 0; i < 4; i++)
                #pragma unroll
                for (int j = 0; j < 4; j++) acc[i][j] = fmaf(a[i], b[j], acc[i][j]);
        }
        __syncthreads();
    }
    #pragma unroll
    for (int i = 0; i < 4; i++)
        #pragma unroll
        for (int j = 0; j < 4; j++)
            C[(size_t)(by * 64 + ty * 4 + i) * Nd + bx * 64 + tx * 4 + j] = acc[i][j];
}

// ---------------- aggregation + skip + bias + activation ----------------
// out[i,f] = act( P[i,f]*skip[f] + inv[i]*sum_{j in N(i)} P[j,f] + b[f] )
// ACT==1: relu(selu(x)) == x>0 ? 1.0507...*x : 0 ; ACT==0: identity
template <int ACT>
__global__ __launch_bounds__(256) void k_aggregate(const float* __restrict__ P, float* __restrict__ OUT,
        const float* __restrict__ skip, const float* __restrict__ bias,
        const float* __restrict__ inv, const unsigned int* __restrict__ mask, int Fd) {
    __shared__ unsigned short list[NPTS];
    __shared__ int cnt;
    int i = blockIdx.x, tid = threadIdx.x;
    if (tid == 0) cnt = 0;
    __syncthreads();
    unsigned int w = mask[(size_t)i * (NPTS / 32) + tid];  // 256 words, 256 threads
    while (w) {
        int b = __ffs(w) - 1;
        w &= w - 1;
        int pos = atomicAdd(&cnt, 1);
        list[pos] = (unsigned short)(tid * 32 + b);
    }
    __syncthreads();
    int n = cnt;
    float vinv = inv[i];
    for (int f = tid; f < Fd; f += 256) {
        float s = 0.f;
        for (int q = 0; q < n; q++) s += P[(size_t)list[q] * Fd + f];
        float o = P[(size_t)i * Fd + f] * skip[f] + vinv * s + bias[f];
        if (ACT == 1) o = (o > 0.f) ? 1.0507009873554805f * o : 0.f;
        OUT[(size_t)i * Fd + f] = o;
    }
}

// ---------------- logits + softmax -> assign ----------------
__global__ void k_assign(const float* __restrict__ emb, const float* __restrict__ Wt,
                         const float* __restrict__ bt, float* __restrict__ assign) {
    int i = blockIdx.x, lane = threadIdx.x;  // 64 threads
    float e[4];
    #pragma unroll
    for (int m = 0; m < 4; m++) e[m] = emb[(size_t)i * FOUT + lane + 64 * m];
    float logit[NCLU];
    #pragma unroll
    for (int c = 0; c < NCLU; c++) {
        float p = 0.f;
        #pragma unroll
        for (int m = 0; m < 4; m++) p = fmaf(e[m], Wt[c * FOUT + lane + 64 * m], p);
        #pragma unroll
        for (int off = 32; off > 0; off >>= 1) p += __shfl_xor(p, off);
        logit[c] = p + bt[c];
    }
    float mx = logit[0];
    #pragma unroll
    for (int c = 1; c < NCLU; c++) mx = fmaxf(mx, logit[c]);
    float sum = 0.f, pr[NCLU];
    #pragma unroll
    for (int c = 0; c < NCLU; c++) { pr[c] = expf(logit[c] - mx); sum += pr[c]; }
    float isum = 1.f / sum;
    if (lane < NCLU) {
        float v = 0.f;
        #pragma unroll
        for (int c = 0; c < NCLU; c++) if (lane == c) v = pr[c];
        assign[(size_t)i * NCLU + lane] = v * isum;
    }
}

// ---------------- spectral reductions: T1 and v[c] ----------------
__global__ __launch_bounds__(256) void k_spectral(const unsigned int* __restrict__ mask,
        const float* __restrict__ assign, const float* __restrict__ degf,
        float* __restrict__ T1, float* __restrict__ v) {
    __shared__ float red[4][NCLU];
    int i = blockIdx.x, tid = threadIdx.x;
    float yc[NCLU];
    #pragma unroll
    for (int c = 0; c < NCLU; c++) yc[c] = 0.f;
    unsigned int w = mask[(size_t)i * (NPTS / 32) + tid];
    while (w) {
        int b = __ffs(w) - 1;
        w &= w - 1;
        int j = tid * 32 + b;
        const float* aj = assign + (size_t)j * NCLU;
        #pragma unroll
        for (int c = 0; c < NCLU; c++) yc[c] += aj[c];
    }
    #pragma unroll
    for (int c = 0; c < NCLU; c++) {
        #pragma unroll
        for (int off = 32; off > 0; off >>= 1) yc[c] += __shfl_xor(yc[c], off);
    }
    int wv = tid >> 6, lane = tid & 63;
    if (lane == 0) {
        #pragma unroll
        for (int c = 0; c < NCLU; c++) red[wv][c] = yc[c];
    }
    __syncthreads();
    if (tid == 0) {
        const float* ai = assign + (size_t)i * NCLU;
        float t = 0.f;
        #pragma unroll
        for (int c = 0; c < NCLU; c++) {
            float y = red[0][c] + red[1][c] + red[2][c] + red[3][c];
            t = fmaf(y, ai[c], t);
        }
        atomicAdd(T1, t);
        float d = degf[i];
        #pragma unroll
        for (int c = 0; c < NCLU; c++) atomicAdd(&v[c], ai[c] * d);
    }
}

// ---------------- final scalar ----------------
__global__ void k_final(const float* __restrict__ T1, const float* __restrict__ v,
                        const float* __restrict__ Esum, float* __restrict__ out) {
    float E = *Esum;
    float v2 = 0.f;
    for (int c = 0; c < NCLU; c++) v2 += v[c] * v[c];
    float tr_norm = v2 / (2.f * E);
    out[0] = -((*T1) - tr_norm) / (2.f * E);
}

extern "C" void kernel_launch(void* const* d_in, const int* in_sizes, int n_in,
                              void* d_out, int out_size, void* d_ws, size_t ws_size,
                              hipStream_t stream) {
    const float* x     = (const float*)d_in[0];
    const float* W1    = (const float*)d_in[1];
    const float* b1    = (const float*)d_in[2];
    const float* skip1 = (const float*)d_in[3];
    const float* W2    = (const float*)d_in[4];
    const float* b2    = (const float*)d_in[5];
    const float* skip2 = (const float*)d_in[6];
    const float* Wt    = (const float*)d_in[7];
    const float* bt    = (const float*)d_in[8];

    char* ws = (char*)d_ws;
    float* bufA = (float*)ws;                                   // 16 MB  [N x 512]
    float* bufB = (float*)(ws + ((size_t)16 << 20));            // 16 MB  [N x 512]
    unsigned int* mask = (unsigned int*)(ws + ((size_t)32 << 20)); // 8 MB bitmask
    char* p = ws + ((size_t)40 << 20);
    float* sq     = (float*)p; p += NPTS * 4;
    float* degf   = (float*)p; p += NPTS * 4;
    float* inv    = (float*)p; p += NPTS * 4;
    int*   topidx = (int*)p;   p += (size_t)NPTS * KNEI * 4;
    float* assign = (float*)p; p += (size_t)NPTS * NCLU * 4;
    float* Esum   = (float*)p; p += 4;
    float* T1     = (float*)p; p += 4;
    float* vvec   = (float*)p; p += NCLU * 4;

    hipMemsetAsync(mask, 0, (size_t)NPTS * (NPTS / 8 / 4) * 4, stream); // 8 MB
    hipMemsetAsync(Esum, 0, (2 + NCLU) * sizeof(float), stream);

    k_sumsq<<<NPTS, 256, 0, stream>>>(x, sq);
    k_gram_topk<<<NPTS / GR_ROWS, 256, 0, stream>>>(x, sq, topidx);
    k_set_edges<<<(NPTS * KNEI + 255) / 256, 256, 0, stream>>>(topidx, mask);
    k_degree<<<NPTS, 64, 0, stream>>>(mask, degf, inv, Esum);

    // layer 1: P = x @ W1 ; h = act1(P*skip1 + A_hat@P + b1)
    k_gemm<<<dim3(FHID / 64, NPTS / 64), 256, 0, stream>>>(x, W1, bufA, NPTS, FIN, FHID);
    k_aggregate<1><<<NPTS, 256, 0, stream>>>(bufA, bufB, skip1, b1, inv, mask, FHID);
    // layer 2: P2 = h @ W2 ; emb = P2*skip2 + A_hat@P2 + b2
    k_gemm<<<dim3(FOUT / 64, NPTS / 64), 256, 0, stream>>>(bufB, W2, bufA, NPTS, FHID, FOUT);
    k_aggregate<0><<<NPTS, 256, 0, stream>>>(bufA, bufB, skip2, b2, inv, mask, FOUT);

    k_assign<<<NPTS, 64, 0, stream>>>(bufB, Wt, bt, assign);
    k_spectral<<<NPTS, 256, 0, stream>>>(mask, assign, degf, T1, vvec);
    k_final<<<1, 1, 0, stream>>>(T1, vvec, Esum, (float*)d_out);
}

// Round 6
// 4348.859 us; speedup vs baseline: 1.3894x; 1.3894x over previous
//
#include <hip/hip_runtime.h>
#include <math.h>
#include <stdint.h>

#define NPTS 8192
#define FIN 512
#define FHID 512
#define FOUT 256
#define NCLU 10
#define KNEI 10
#define GAMMA_F 2.0f

typedef __attribute__((ext_vector_type(4))) float f32x4;
typedef __attribute__((ext_vector_type(8))) short bf16x8;

// ---------------- sum of squares per row ----------------
__global__ void k_sumsq(const float* __restrict__ x, float* __restrict__ sq) {
    int row = blockIdx.x;
    const float* xr = x + (size_t)row * FIN;
    float s = 0.f;
    for (int k = threadIdx.x; k < FIN; k += 256) s += xr[k] * xr[k];
    __shared__ float red[256];
    red[threadIdx.x] = s; __syncthreads();
    for (int off = 128; off > 0; off >>= 1) {
        if (threadIdx.x < off) red[threadIdx.x] += red[threadIdx.x + off];
        __syncthreads();
    }
    if (threadIdx.x == 0) sq[row] = red[0];
}

// ---------------- f32 -> bf16 (RNE) ----------------
__global__ void k_tobf16(const float* __restrict__ x, unsigned short* __restrict__ xb) {
    int i = blockIdx.x * 256 + threadIdx.x;   // one float4 per thread
    f32x4 v = reinterpret_cast<const f32x4*>(x)[i];
    ushort4 o;
    #pragma unroll
    for (int e = 0; e < 4; e++) {
        union { float f; unsigned u; } cvt; cvt.f = v[e];
        unsigned r = (cvt.u + 0x7FFFu + ((cvt.u >> 16) & 1u)) >> 16;
        ((unsigned short*)&o)[e] = (unsigned short)r;
    }
    reinterpret_cast<ushort4*>(xb)[i] = o;
}

// ---------------- fused MFMA gram + exp + per-row top-10 ----------------
// block: 256 threads (4 waves), owns GR_ROWS=16 rows; iterates 16 col tiles of 512.
// wave w computes rows 0..15 x cols [w*128, w*128+128) via 8 col-frags x 16 K-steps MFMA.
#define GR_ROWS 16
#define GR_BN 512
#define GR_TILES (NPTS / GR_BN)   // 16

__global__ __launch_bounds__(256, 2) void k_gram_topk(
    const unsigned short* __restrict__ xb, const float* __restrict__ sq, int* __restrict__ topidx)
{
    __shared__ float Sl[GR_ROWS][GR_BN + 1];
    __shared__ float tval[GR_ROWS][KNEI];
    __shared__ int   tidxs[GR_ROWS][KNEI];

    const int tid  = threadIdx.x;
    const int lane = tid & 63;
    const int wv   = tid >> 6;            // 0..3
    const int r0   = blockIdx.x * GR_ROWS;

    if (tid < GR_ROWS * KNEI) {
        tval[tid / KNEI][tid % KNEI] = -INFINITY;
        tidxs[tid / KNEI][tid % KNEI] = 0x7fffffff;
    }
    __syncthreads();

    // A fragments for the block's 16 rows, all K: lane l -> row (l&15), k = ks*32 + (l>>4)*8 .. +8
    const int arow  = r0 + (lane & 15);
    const int akoff = (lane >> 4) * 8;
    bf16x8 afr[16];
    #pragma unroll
    for (int ks = 0; ks < 16; ks++)
        afr[ks] = *reinterpret_cast<const bf16x8*>(xb + (size_t)arow * FIN + ks * 32 + akoff);

    float si_r[4];   // sq for the 4 output rows this lane produces: row = (lane>>4)*4 + r
    #pragma unroll
    for (int r = 0; r < 4; r++) si_r[r] = sq[r0 + (lane >> 4) * 4 + r];

    for (int t = 0; t < GR_TILES; ++t) {
        const int c0 = t * GR_BN + wv * 128;    // wave's global col base
        f32x4 acc[8];
        #pragma unroll
        for (int ct = 0; ct < 8; ct++) acc[ct] = (f32x4){0.f, 0.f, 0.f, 0.f};

        #pragma unroll
        for (int ks = 0; ks < 16; ks++) {
            #pragma unroll
            for (int ct = 0; ct < 8; ct++) {
                const int j = c0 + ct * 16 + (lane & 15);
                bf16x8 bfr = *reinterpret_cast<const bf16x8*>(xb + (size_t)j * FIN + ks * 32 + akoff);
                acc[ct] = __builtin_amdgcn_mfma_f32_16x16x32_bf16(afr[ks], bfr, acc[ct], 0, 0, 0);
            }
        }

        // epilogue: S = exp(-d2/2), diag = -inf; C layout: col=lane&15, row=(lane>>4)*4+reg
        #pragma unroll
        for (int ct = 0; ct < 8; ct++) {
            const int col = wv * 128 + ct * 16 + (lane & 15);
            const int gj  = t * GR_BN + col;
            const float sjv = sq[gj];
            #pragma unroll
            for (int r = 0; r < 4; r++) {
                const int row = (lane >> 4) * 4 + r;
                const int gi  = r0 + row;
                const float d2 = si_r[r] + sjv - 2.f * acc[ct][r];
                Sl[row][col] = (gj == gi) ? -INFINITY : expf(-d2 * 0.5f);
            }
        }
        __syncthreads();

        // top-10 update, strict order (val desc, idx asc). wave w owns rows 4w..4w+3.
        for (int q = 0; q < 4; ++q) {
            int r = wv * 4 + q;
            for (int base = 0; base < GR_BN; base += 64) {
                float v = Sl[r][base + lane];
                int gj = t * GR_BN + base + lane;
                float rv9 = tval[r][KNEI - 1];
                int ri9 = tidxs[r][KNEI - 1];
                unsigned long long bal = __ballot(v > rv9 || (v == rv9 && gj < ri9));
                if (lane == 0 && bal) {
                    while (bal) {
                        int l = __ffsll((unsigned long long)bal) - 1;
                        bal &= bal - 1;
                        float cv = Sl[r][base + l];
                        int cj = t * GR_BN + base + l;
                        float a9 = tval[r][KNEI - 1];
                        int i9 = tidxs[r][KNEI - 1];
                        if (cv > a9 || (cv == a9 && cj < i9)) {
                            int pp = KNEI - 1;
                            tval[r][pp] = cv; tidxs[r][pp] = cj;
                            while (pp > 0) {
                                float pv = tval[r][pp - 1]; int pi = tidxs[r][pp - 1];
                                if (cv > pv || (cv == pv && cj < pi)) {
                                    tval[r][pp] = pv; tidxs[r][pp] = pi;
                                    tval[r][pp - 1] = cv; tidxs[r][pp - 1] = cj;
                                    --pp;
                                } else break;
                            }
                        }
                    }
                }
            }
        }
        __syncthreads();
    }

    if (tid < GR_ROWS * KNEI) {
        int r = tid / KNEI, m = tid % KNEI;
        topidx[(size_t)(r0 + r) * KNEI + m] = tidxs[r][m];
    }
}

// ---------------- build symmetric adjacency bitmask ----------------
__global__ void k_set_edges(const int* __restrict__ topidx, unsigned int* __restrict__ mask) {
    int t = blockIdx.x * 256 + threadIdx.x;
    if (t >= NPTS * KNEI) return;
    int i = t / KNEI;
    int j = topidx[t];
    atomicOr(&mask[(size_t)i * (NPTS / 32) + (j >> 5)], 1u << (j & 31));
    atomicOr(&mask[(size_t)j * (NPTS / 32) + (i >> 5)], 1u << (i & 31));
}

// ---------------- degree, inv, total edges ----------------
__global__ void k_degree(const unsigned int* __restrict__ mask, float* __restrict__ degf,
                         float* __restrict__ inv, float* __restrict__ Esum) {
    int i = blockIdx.x, lane = threadIdx.x;  // 64 threads
    int c = 0;
    for (int w = lane; w < NPTS / 32; w += 64) c += __popc(mask[(size_t)i * (NPTS / 32) + w]);
    for (int off = 32; off > 0; off >>= 1) c += __shfl_xor(c, off);
    if (lane == 0) {
        float d = (float)c;
        degf[i] = d;
        inv[i] = (c > 0) ? 1.0f / d : 0.0f;
        atomicAdd(Esum, d);
    }
}

// ---------------- generic f32 GEMM: C[M,Nd] = A[M,Kd] @ B[Kd,Nd] ----------------
__global__ __launch_bounds__(256) void k_gemm(const float* __restrict__ A, const float* __restrict__ B,
                                              float* __restrict__ C, int M, int Kd, int Nd) {
    __shared__ float Al[64][17];
    __shared__ float Bl[16][65];
    int tid = threadIdx.x;
    int bx = blockIdx.x, by = blockIdx.y;
    int tx = tid & 15, ty = tid >> 4;
    float acc[4][4];
    #pragma unroll
    for (int i = 0; i < 4; i++)
        #pragma unroll
        for (int j = 0; j < 4; j++) acc[i][j] = 0.f;

    for (int kt = 0; kt < Kd; kt += 16) {
        #pragma unroll
        for (int l = 0; l < 4; l++) {
            int e = tid + l * 256;
            int r = e >> 4, k = e & 15;
            Al[r][k] = A[(size_t)(by * 64 + r) * Kd + kt + k];
        }
        #pragma unroll
        for (int l = 0; l < 4; l++) {
            int e = tid + l * 256;
            int r = e >> 6, n = e & 63;
            Bl[r][n] = B[(size_t)(kt + r) * Nd + bx * 64 + n];
        }
        __syncthreads();
        #pragma unroll
        for (int k = 0; k < 16; k++) {
            float a[4], b[4];
            #pragma unroll
            for (int i = 0; i < 4; i++) a[i] = Al[ty * 4 + i][k];
            #pragma unroll
            for (int j = 0; j < 4; j++) b[j] = Bl[k][tx * 4 + j];
            #pragma unroll
            for (int i = 0; i < 4; i++)
                #pragma unroll
                for (int j = 0; j < 4; j++) acc[i][j] = fmaf(a[i], b[j], acc[i][j]);
        }
        __syncthreads();
    }
    #pragma unroll
    for (int i = 0; i < 4; i++)
        #pragma unroll
        for (int j = 0; j < 4; j++)
            C[(size_t)(by * 64 + ty * 4 + i) * Nd + bx * 64 + tx * 4 + j] = acc[i][j];
}

// ---------------- aggregation + skip + bias + activation ----------------
// out[i,f] = act( P[i,f]*skip[f] + inv[i]*sum_{j in N(i)} P[j,f] + b[f] )
// ACT==1: relu(selu(x)) == x>0 ? 1.0507...*x : 0 ; ACT==0: identity
template <int ACT>
__global__ __launch_bounds__(256) void k_aggregate(const float* __restrict__ P, float* __restrict__ OUT,
        const float* __restrict__ skip, const float* __restrict__ bias,
        const float* __restrict__ inv, const unsigned int* __restrict__ mask, int Fd) {
    __shared__ unsigned short list[NPTS];
    __shared__ int cnt;
    int i = blockIdx.x, tid = threadIdx.x;
    if (tid == 0) cnt = 0;
    __syncthreads();
    unsigned int w = mask[(size_t)i * (NPTS / 32) + tid];  // 256 words, 256 threads
    while (w) {
        int b = __ffs(w) - 1;
        w &= w - 1;
        int pos = atomicAdd(&cnt, 1);
        list[pos] = (unsigned short)(tid * 32 + b);
    }
    __syncthreads();
    int n = cnt;
    float vinv = inv[i];
    for (int f = tid; f < Fd; f += 256) {
        float s = 0.f;
        for (int q = 0; q < n; q++) s += P[(size_t)list[q] * Fd + f];
        float o = P[(size_t)i * Fd + f] * skip[f] + vinv * s + bias[f];
        if (ACT == 1) o = (o > 0.f) ? 1.0507009873554805f * o : 0.f;
        OUT[(size_t)i * Fd + f] = o;
    }
}

// ---------------- logits + softmax -> assign ----------------
__global__ void k_assign(const float* __restrict__ emb, const float* __restrict__ Wt,
                         const float* __restrict__ bt, float* __restrict__ assign) {
    int i = blockIdx.x, lane = threadIdx.x;  // 64 threads
    float e[4];
    #pragma unroll
    for (int m = 0; m < 4; m++) e[m] = emb[(size_t)i * FOUT + lane + 64 * m];
    float logit[NCLU];
    #pragma unroll
    for (int c = 0; c < NCLU; c++) {
        float p = 0.f;
        #pragma unroll
        for (int m = 0; m < 4; m++) p = fmaf(e[m], Wt[c * FOUT + lane + 64 * m], p);
        #pragma unroll
        for (int off = 32; off > 0; off >>= 1) p += __shfl_xor(p, off);
        logit[c] = p + bt[c];
    }
    float mx = logit[0];
    #pragma unroll
    for (int c = 1; c < NCLU; c++) mx = fmaxf(mx, logit[c]);
    float sum = 0.f, pr[NCLU];
    #pragma unroll
    for (int c = 0; c < NCLU; c++) { pr[c] = expf(logit[c] - mx); sum += pr[c]; }
    float isum = 1.f / sum;
    if (lane < NCLU) {
        float v = 0.f;
        #pragma unroll
        for (int c = 0; c < NCLU; c++) if (lane == c) v = pr[c];
        assign[(size_t)i * NCLU + lane] = v * isum;
    }
}

// ---------------- spectral reductions: T1 and v[c] ----------------
__global__ __launch_bounds__(256) void k_spectral(const unsigned int* __restrict__ mask,
        const float* __restrict__ assign, const float* __restrict__ degf,
        float* __restrict__ T1, float* __restrict__ v) {
    __shared__ float red[4][NCLU];
    int i = blockIdx.x, tid = threadIdx.x;
    float yc[NCLU];
    #pragma unroll
    for (int c = 0; c < NCLU; c++) yc[c] = 0.f;
    unsigned int w = mask[(size_t)i * (NPTS / 32) + tid];
    while (w) {
        int b = __ffs(w) - 1;
        w &= w - 1;
        int j = tid * 32 + b;
        const float* aj = assign + (size_t)j * NCLU;
        #pragma unroll
        for (int c = 0; c < NCLU; c++) yc[c] += aj[c];
    }
    #pragma unroll
    for (int c = 0; c < NCLU; c++) {
        #pragma unroll
        for (int off = 32; off > 0; off >>= 1) yc[c] += __shfl_xor(yc[c], off);
    }
    int wv = tid >> 6, lane = tid & 63;
    if (lane == 0) {
        #pragma unroll
        for (int c = 0; c < NCLU; c++) red[wv][c] = yc[c];
    }
    __syncthreads();
    if (tid == 0) {
        const float* ai = assign + (size_t)i * NCLU;
        float t = 0.f;
        #pragma unroll
        for (int c = 0; c < NCLU; c++) {
            float y = red[0][c] + red[1][c] + red[2][c] + red[3][c];
            t = fmaf(y, ai[c], t);
        }
        atomicAdd(T1, t);
        float d = degf[i];
        #pragma unroll
        for (int c = 0; c < NCLU; c++) atomicAdd(&v[c], ai[c] * d);
    }
}

// ---------------- final scalar ----------------
__global__ void k_final(const float* __restrict__ T1, const float* __restrict__ v,
                        const float* __restrict__ Esum, float* __restrict__ out) {
    float E = *Esum;
    float v2 = 0.f;
    for (int c = 0; c < NCLU; c++) v2 += v[c] * v[c];
    float tr_norm = v2 / (2.f * E);
    out[0] = -((*T1) - tr_norm) / (2.f * E);
}

extern "C" void kernel_launch(void* const* d_in, const int* in_sizes, int n_in,
                              void* d_out, int out_size, void* d_ws, size_t ws_size,
                              hipStream_t stream) {
    const float* x     = (const float*)d_in[0];
    const float* W1    = (const float*)d_in[1];
    const float* b1    = (const float*)d_in[2];
    const float* skip1 = (const float*)d_in[3];
    const float* W2    = (const float*)d_in[4];
    const float* b2    = (const float*)d_in[5];
    const float* skip2 = (const float*)d_in[6];
    const float* Wt    = (const float*)d_in[7];
    const float* bt    = (const float*)d_in[8];

    char* ws = (char*)d_ws;
    float* bufA = (float*)ws;                                   // 16 MB  [N x 512]
    float* bufB = (float*)(ws + ((size_t)16 << 20));            // 16 MB  [N x 512]
    unsigned int* mask = (unsigned int*)(ws + ((size_t)32 << 20)); // 8 MB bitmask
    char* p = ws + ((size_t)40 << 20);
    float* sq     = (float*)p; p += NPTS * 4;
    float* degf   = (float*)p; p += NPTS * 4;
    float* inv    = (float*)p; p += NPTS * 4;
    int*   topidx = (int*)p;   p += (size_t)NPTS * KNEI * 4;
    float* assign = (float*)p; p += (size_t)NPTS * NCLU * 4;
    float* Esum   = (float*)p; p += 4;
    float* T1     = (float*)p; p += 4;
    float* vvec   = (float*)p; p += NCLU * 4;

    // xb (bf16 copy of x, 8MB) aliases bufA: dead before k_gemm writes bufA.
    unsigned short* xb = (unsigned short*)bufA;

    hipMemsetAsync(mask, 0, (size_t)NPTS * (NPTS / 32) * 4, stream); // 8 MB
    hipMemsetAsync(Esum, 0, (2 + NCLU) * sizeof(float), stream);

    k_sumsq<<<NPTS, 256, 0, stream>>>(x, sq);
    k_tobf16<<<(NPTS * FIN / 4) / 256, 256, 0, stream>>>(x, xb);
    k_gram_topk<<<NPTS / GR_ROWS, 256, 0, stream>>>(xb, sq, topidx);
    k_set_edges<<<(NPTS * KNEI + 255) / 256, 256, 0, stream>>>(topidx, mask);
    k_degree<<<NPTS, 64, 0, stream>>>(mask, degf, inv, Esum);

    // layer 1: P = x @ W1 ; h = act1(P*skip1 + A_hat@P + b1)
    k_gemm<<<dim3(FHID / 64, NPTS / 64), 256, 0, stream>>>(x, W1, bufA, NPTS, FIN, FHID);
    k_aggregate<1><<<NPTS, 256, 0, stream>>>(bufA, bufB, skip1, b1, inv, mask, FHID);
    // layer 2: P2 = h @ W2 ; emb = P2*skip2 + A_hat@P2 + b2
    k_gemm<<<dim3(FOUT / 64, NPTS / 64), 256, 0, stream>>>(bufB, W2, bufA, NPTS, FHID, FOUT);
    k_aggregate<0><<<NPTS, 256, 0, stream>>>(bufA, bufB, skip2, b2, inv, mask, FOUT);

    k_assign<<<NPTS, 64, 0, stream>>>(bufB, Wt, bt, assign);
    k_spectral<<<NPTS, 256, 0, stream>>>(mask, assign, degf, T1, vvec);
    k_final<<<1, 1, 0, stream>>>(T1, vvec, Esum, (float*)d_out);
}

// Round 7
// 2383.678 us; speedup vs baseline: 2.5349x; 1.8244x over previous
//
#include <hip/hip_runtime.h>
#include <math.h>
#include <stdint.h>

#define NPTS 8192
#define FIN 512
#define FHID 512
#define FOUT 256
#define NCLU 10
#define KNEI 10
#define GAMMA_F 2.0f
#define LISTCAP 4160   // > 4096 direct cap and > 4095 complement cap

typedef __attribute__((ext_vector_type(4))) float f32x4;
typedef __attribute__((ext_vector_type(8))) short bf16x8;

// ---------------- sum of squares per row ----------------
__global__ void k_sumsq(const float* __restrict__ x, float* __restrict__ sq) {
    int row = blockIdx.x;
    const float* xr = x + (size_t)row * FIN;
    float s = 0.f;
    for (int k = threadIdx.x; k < FIN; k += 256) s += xr[k] * xr[k];
    __shared__ float red[256];
    red[threadIdx.x] = s; __syncthreads();
    for (int off = 128; off > 0; off >>= 1) {
        if (threadIdx.x < off) red[threadIdx.x] += red[threadIdx.x + off];
        __syncthreads();
    }
    if (threadIdx.x == 0) sq[row] = red[0];
}

// ---------------- f32 -> bf16 (RNE) ----------------
__global__ void k_tobf16(const float* __restrict__ x, unsigned short* __restrict__ xb) {
    int i = blockIdx.x * 256 + threadIdx.x;   // one float4 per thread
    f32x4 v = reinterpret_cast<const f32x4*>(x)[i];
    ushort4 o;
    #pragma unroll
    for (int e = 0; e < 4; e++) {
        union { float f; unsigned u; } cvt; cvt.f = v[e];
        unsigned r = (cvt.u + 0x7FFFu + ((cvt.u >> 16) & 1u)) >> 16;
        ((unsigned short*)&o)[e] = (unsigned short)r;
    }
    reinterpret_cast<ushort4*>(xb)[i] = o;
}

// ---------------- fused MFMA gram + exp + per-row top-10 ----------------
#define GR_ROWS 16
#define GR_BN 512
#define GR_TILES (NPTS / GR_BN)   // 16

__global__ __launch_bounds__(256, 2) void k_gram_topk(
    const unsigned short* __restrict__ xb, const float* __restrict__ sq, int* __restrict__ topidx)
{
    __shared__ float Sl[GR_ROWS][GR_BN + 1];
    __shared__ float tval[GR_ROWS][KNEI];
    __shared__ int   tidxs[GR_ROWS][KNEI];

    const int tid  = threadIdx.x;
    const int lane = tid & 63;
    const int wv   = tid >> 6;            // 0..3
    const int r0   = blockIdx.x * GR_ROWS;

    if (tid < GR_ROWS * KNEI) {
        tval[tid / KNEI][tid % KNEI] = -INFINITY;
        tidxs[tid / KNEI][tid % KNEI] = 0x7fffffff;
    }
    __syncthreads();

    const int arow  = r0 + (lane & 15);
    const int akoff = (lane >> 4) * 8;
    bf16x8 afr[16];
    #pragma unroll
    for (int ks = 0; ks < 16; ks++)
        afr[ks] = *reinterpret_cast<const bf16x8*>(xb + (size_t)arow * FIN + ks * 32 + akoff);

    float si_r[4];
    #pragma unroll
    for (int r = 0; r < 4; r++) si_r[r] = sq[r0 + (lane >> 4) * 4 + r];

    for (int t = 0; t < GR_TILES; ++t) {
        const int c0 = t * GR_BN + wv * 128;
        f32x4 acc[8];
        #pragma unroll
        for (int ct = 0; ct < 8; ct++) acc[ct] = (f32x4){0.f, 0.f, 0.f, 0.f};

        #pragma unroll
        for (int ks = 0; ks < 16; ks++) {
            #pragma unroll
            for (int ct = 0; ct < 8; ct++) {
                const int j = c0 + ct * 16 + (lane & 15);
                bf16x8 bfr = *reinterpret_cast<const bf16x8*>(xb + (size_t)j * FIN + ks * 32 + akoff);
                acc[ct] = __builtin_amdgcn_mfma_f32_16x16x32_bf16(afr[ks], bfr, acc[ct], 0, 0, 0);
            }
        }

        #pragma unroll
        for (int ct = 0; ct < 8; ct++) {
            const int col = wv * 128 + ct * 16 + (lane & 15);
            const int gj  = t * GR_BN + col;
            const float sjv = sq[gj];
            #pragma unroll
            for (int r = 0; r < 4; r++) {
                const int row = (lane >> 4) * 4 + r;
                const int gi  = r0 + row;
                const float d2 = si_r[r] + sjv - 2.f * acc[ct][r];
                Sl[row][col] = (gj == gi) ? -INFINITY : expf(-d2 * 0.5f);
            }
        }
        __syncthreads();

        for (int q = 0; q < 4; ++q) {
            int r = wv * 4 + q;
            for (int base = 0; base < GR_BN; base += 64) {
                float v = Sl[r][base + lane];
                int gj = t * GR_BN + base + lane;
                float rv9 = tval[r][KNEI - 1];
                int ri9 = tidxs[r][KNEI - 1];
                unsigned long long bal = __ballot(v > rv9 || (v == rv9 && gj < ri9));
                if (lane == 0 && bal) {
                    while (bal) {
                        int l = __ffsll((unsigned long long)bal) - 1;
                        bal &= bal - 1;
                        float cv = Sl[r][base + l];
                        int cj = t * GR_BN + base + l;
                        float a9 = tval[r][KNEI - 1];
                        int i9 = tidxs[r][KNEI - 1];
                        if (cv > a9 || (cv == a9 && cj < i9)) {
                            int pp = KNEI - 1;
                            tval[r][pp] = cv; tidxs[r][pp] = cj;
                            while (pp > 0) {
                                float pv = tval[r][pp - 1]; int pi = tidxs[r][pp - 1];
                                if (cv > pv || (cv == pv && cj < pi)) {
                                    tval[r][pp] = pv; tidxs[r][pp] = pi;
                                    tval[r][pp - 1] = cv; tidxs[r][pp - 1] = cj;
                                    --pp;
                                } else break;
                            }
                        }
                    }
                }
            }
        }
        __syncthreads();
    }

    if (tid < GR_ROWS * KNEI) {
        int r = tid / KNEI, m = tid % KNEI;
        topidx[(size_t)(r0 + r) * KNEI + m] = tidxs[r][m];
    }
}

// ---------------- build symmetric adjacency bitmask ----------------
__global__ void k_set_edges(const int* __restrict__ topidx, unsigned int* __restrict__ mask) {
    int t = blockIdx.x * 256 + threadIdx.x;
    if (t >= NPTS * KNEI) return;
    int i = t / KNEI;
    int j = topidx[t];
    atomicOr(&mask[(size_t)i * (NPTS / 32) + (j >> 5)], 1u << (j & 31));
    atomicOr(&mask[(size_t)j * (NPTS / 32) + (i >> 5)], 1u << (i & 31));
}

// ---------------- degree, inv, total edges ----------------
__global__ void k_degree(const unsigned int* __restrict__ mask, float* __restrict__ degf,
                         float* __restrict__ inv, float* __restrict__ Esum) {
    int i = blockIdx.x, lane = threadIdx.x;  // 64 threads
    int c = 0;
    for (int w = lane; w < NPTS / 32; w += 64) c += __popc(mask[(size_t)i * (NPTS / 32) + w]);
    for (int off = 32; off > 0; off >>= 1) c += __shfl_xor(c, off);
    if (lane == 0) {
        float d = (float)c;
        degf[i] = d;
        inv[i] = (c > 0) ? 1.0f / d : 0.0f;
        atomicAdd(Esum, d);
    }
}

// ---------------- generic f32 GEMM ----------------
__global__ __launch_bounds__(256) void k_gemm(const float* __restrict__ A, const float* __restrict__ B,
                                              float* __restrict__ C, int M, int Kd, int Nd) {
    __shared__ float Al[64][17];
    __shared__ float Bl[16][65];
    int tid = threadIdx.x;
    int bx = blockIdx.x, by = blockIdx.y;
    int tx = tid & 15, ty = tid >> 4;
    float acc[4][4];
    #pragma unroll
    for (int i = 0; i < 4; i++)
        #pragma unroll
        for (int j = 0; j < 4; j++) acc[i][j] = 0.f;

    for (int kt = 0; kt < Kd; kt += 16) {
        #pragma unroll
        for (int l = 0; l < 4; l++) {
            int e = tid + l * 256;
            int r = e >> 4, k = e & 15;
            Al[r][k] = A[(size_t)(by * 64 + r) * Kd + kt + k];
        }
        #pragma unroll
        for (int l = 0; l < 4; l++) {
            int e = tid + l * 256;
            int r = e >> 6, n = e & 63;
            Bl[r][n] = B[(size_t)(kt + r) * Nd + bx * 64 + n];
        }
        __syncthreads();
        #pragma unroll
        for (int k = 0; k < 16; k++) {
            float a[4], b[4];
            #pragma unroll
            for (int i = 0; i < 4; i++) a[i] = Al[ty * 4 + i][k];
            #pragma unroll
            for (int j = 0; j < 4; j++) b[j] = Bl[k][tx * 4 + j];
            #pragma unroll
            for (int i = 0; i < 4; i++)
                #pragma unroll
                for (int j = 0; j < 4; j++) acc[i][j] = fmaf(a[i], b[j], acc[i][j]);
        }
        __syncthreads();
    }
    #pragma unroll
    for (int i = 0; i < 4; i++)
        #pragma unroll
        for (int j = 0; j < 4; j++)
            C[(size_t)(by * 64 + ty * 4 + i) * Nd + bx * 64 + tx * 4 + j] = acc[i][j];
}

// ---------------- column sums of P: colsum[f] = sum_j P[j,f] ----------------
// grid: (Fd/256, 64); each block sums 128 rows. colsum must be pre-zeroed.
__global__ __launch_bounds__(256) void k_colsum(const float* __restrict__ P, float* __restrict__ colsum, int Fd) {
    int f = blockIdx.x * 256 + threadIdx.x;
    int r0 = blockIdx.y * (NPTS / 64);
    float s = 0.f;
    for (int r = 0; r < NPTS / 64; r++) s += P[(size_t)(r0 + r) * Fd + f];
    atomicAdd(&colsum[f], s);
}

// ---------------- column sums of assign: colA[c] = sum_j assign[j,c] ----------------
// grid: 32 blocks x 256 threads (one row per thread). colA pre-zeroed.
__global__ __launch_bounds__(256) void k_colsumA(const float* __restrict__ assign, float* __restrict__ colA) {
    __shared__ float lc[NCLU];
    int tid = threadIdx.x;
    if (tid < NCLU) lc[tid] = 0.f;
    __syncthreads();
    int r = blockIdx.x * 256 + tid;
    const float* ar = assign + (size_t)r * NCLU;
    #pragma unroll
    for (int c = 0; c < NCLU; c++) {
        float v = ar[c];
        #pragma unroll
        for (int off = 32; off > 0; off >>= 1) v += __shfl_xor(v, off);
        if ((tid & 63) == 0) atomicAdd(&lc[c], v);
    }
    __syncthreads();
    if (tid < NCLU) atomicAdd(&colA[tid], lc[tid]);
}

// ---------------- aggregation + skip + bias + activation (dual-mode) ----------------
// deg <= 4096: gather direct neighbor list.
// deg >  4096: neighbor_sum = colsum[f] - P[i,f] - sum_{j complement, j!=i} P[j,f]
template <int ACT>
__global__ __launch_bounds__(256) void k_aggregate(const float* __restrict__ P, float* __restrict__ OUT,
        const float* __restrict__ skip, const float* __restrict__ bias,
        const float* __restrict__ inv, const unsigned int* __restrict__ mask,
        const float* __restrict__ colsum, int Fd) {
    __shared__ unsigned short list[LISTCAP];
    __shared__ int cnt_total;
    __shared__ int pos;
    int i = blockIdx.x, tid = threadIdx.x;
    if (tid == 0) { cnt_total = 0; pos = 0; }
    __syncthreads();
    unsigned int w = mask[(size_t)i * (NPTS / 32) + tid];  // 256 words, 256 threads
    atomicAdd(&cnt_total, __popc(w));
    __syncthreads();
    const int deg = cnt_total;
    const bool comp = deg > 4096;
    unsigned int wm = comp ? ~w : w;
    if (comp && tid == (i >> 5)) wm &= ~(1u << (i & 31));   // exclude self from complement
    while (wm) {
        int b = __ffs(wm) - 1;
        wm &= wm - 1;
        int pp = atomicAdd(&pos, 1);
        list[pp] = (unsigned short)(tid * 32 + b);
    }
    __syncthreads();
    const int n = comp ? (NPTS - 1 - deg) : deg;
    const float vinv = inv[i];
    for (int f = tid; f < Fd; f += 256) {
        float s = 0.f;
        for (int q = 0; q < n; q++) s += P[(size_t)list[q] * Fd + f];
        const float pif = P[(size_t)i * Fd + f];
        const float nb = comp ? (colsum[f] - pif - s) : s;
        float o = pif * skip[f] + vinv * nb + bias[f];
        if (ACT == 1) o = (o > 0.f) ? 1.0507009873554805f * o : 0.f;
        OUT[(size_t)i * Fd + f] = o;
    }
}

// ---------------- logits + softmax -> assign ----------------
__global__ void k_assign(const float* __restrict__ emb, const float* __restrict__ Wt,
                         const float* __restrict__ bt, float* __restrict__ assign) {
    int i = blockIdx.x, lane = threadIdx.x;  // 64 threads
    float e[4];
    #pragma unroll
    for (int m = 0; m < 4; m++) e[m] = emb[(size_t)i * FOUT + lane + 64 * m];
    float logit[NCLU];
    #pragma unroll
    for (int c = 0; c < NCLU; c++) {
        float p = 0.f;
        #pragma unroll
        for (int m = 0; m < 4; m++) p = fmaf(e[m], Wt[c * FOUT + lane + 64 * m], p);
        #pragma unroll
        for (int off = 32; off > 0; off >>= 1) p += __shfl_xor(p, off);
        logit[c] = p + bt[c];
    }
    float mx = logit[0];
    #pragma unroll
    for (int c = 1; c < NCLU; c++) mx = fmaxf(mx, logit[c]);
    float sum = 0.f, pr[NCLU];
    #pragma unroll
    for (int c = 0; c < NCLU; c++) { pr[c] = expf(logit[c] - mx); sum += pr[c]; }
    float isum = 1.f / sum;
    if (lane < NCLU) {
        float v = 0.f;
        #pragma unroll
        for (int c = 0; c < NCLU; c++) if (lane == c) v = pr[c];
        assign[(size_t)i * NCLU + lane] = v * isum;
    }
}

// ---------------- spectral reductions: T1 and v[c] (dual-mode) ----------------
__global__ __launch_bounds__(256) void k_spectral(const unsigned int* __restrict__ mask,
        const float* __restrict__ assign, const float* __restrict__ degf,
        const float* __restrict__ colA, float* __restrict__ T1, float* __restrict__ v) {
    __shared__ unsigned short list[LISTCAP];
    __shared__ int cnt_total;
    __shared__ int pos;
    __shared__ float red[4][NCLU];
    int i = blockIdx.x, tid = threadIdx.x;
    if (tid == 0) { cnt_total = 0; pos = 0; }
    __syncthreads();
    unsigned int w = mask[(size_t)i * (NPTS / 32) + tid];
    atomicAdd(&cnt_total, __popc(w));
    __syncthreads();
    const int deg = cnt_total;
    const bool comp = deg > 4096;
    unsigned int wm = comp ? ~w : w;
    if (comp && tid == (i >> 5)) wm &= ~(1u << (i & 31));
    while (wm) {
        int b = __ffs(wm) - 1;
        wm &= wm - 1;
        int pp = atomicAdd(&pos, 1);
        list[pp] = (unsigned short)(tid * 32 + b);
    }
    __syncthreads();
    const int n = comp ? (NPTS - 1 - deg) : deg;
    float yc[NCLU];
    #pragma unroll
    for (int c = 0; c < NCLU; c++) yc[c] = 0.f;
    for (int q = tid; q < n; q += 256) {
        const float* aj = assign + (size_t)list[q] * NCLU;
        #pragma unroll
        for (int c = 0; c < NCLU; c++) yc[c] += aj[c];
    }
    #pragma unroll
    for (int c = 0; c < NCLU; c++) {
        #pragma unroll
        for (int off = 32; off > 0; off >>= 1) yc[c] += __shfl_xor(yc[c], off);
    }
    int wv = tid >> 6, lane = tid & 63;
    if (lane == 0) {
        #pragma unroll
        for (int c = 0; c < NCLU; c++) red[wv][c] = yc[c];
    }
    __syncthreads();
    if (tid == 0) {
        const float* ai = assign + (size_t)i * NCLU;
        float t = 0.f;
        #pragma unroll
        for (int c = 0; c < NCLU; c++) {
            float y = red[0][c] + red[1][c] + red[2][c] + red[3][c];
            if (comp) y = colA[c] - ai[c] - y;
            t = fmaf(y, ai[c], t);
        }
        atomicAdd(T1, t);
        float d = degf[i];
        #pragma unroll
        for (int c = 0; c < NCLU; c++) atomicAdd(&v[c], ai[c] * d);
    }
}

// ---------------- final scalar ----------------
__global__ void k_final(const float* __restrict__ T1, const float* __restrict__ v,
                        const float* __restrict__ Esum, float* __restrict__ out) {
    float E = *Esum;
    float v2 = 0.f;
    for (int c = 0; c < NCLU; c++) v2 += v[c] * v[c];
    float tr_norm = v2 / (2.f * E);
    out[0] = -((*T1) - tr_norm) / (2.f * E);
}

extern "C" void kernel_launch(void* const* d_in, const int* in_sizes, int n_in,
                              void* d_out, int out_size, void* d_ws, size_t ws_size,
                              hipStream_t stream) {
    const float* x     = (const float*)d_in[0];
    const float* W1    = (const float*)d_in[1];
    const float* b1    = (const float*)d_in[2];
    const float* skip1 = (const float*)d_in[3];
    const float* W2    = (const float*)d_in[4];
    const float* b2    = (const float*)d_in[5];
    const float* skip2 = (const float*)d_in[6];
    const float* Wt    = (const float*)d_in[7];
    const float* bt    = (const float*)d_in[8];

    char* ws = (char*)d_ws;
    float* bufA = (float*)ws;                                   // 16 MB  [N x 512]
    float* bufB = (float*)(ws + ((size_t)16 << 20));            // 16 MB  [N x 512]
    unsigned int* mask = (unsigned int*)(ws + ((size_t)32 << 20)); // 8 MB bitmask
    char* p = ws + ((size_t)40 << 20);
    float* sq     = (float*)p; p += NPTS * 4;
    float* degf   = (float*)p; p += NPTS * 4;
    float* inv    = (float*)p; p += NPTS * 4;
    int*   topidx = (int*)p;   p += (size_t)NPTS * KNEI * 4;
    float* assign = (float*)p; p += (size_t)NPTS * NCLU * 4;
    // contiguous zero-region: Esum, T1, vvec[10], colA[10], colsum1[512], colsum2[256]
    float* Esum    = (float*)p; p += 4;
    float* T1      = (float*)p; p += 4;
    float* vvec    = (float*)p; p += NCLU * 4;
    float* colA    = (float*)p; p += NCLU * 4;
    float* colsum1 = (float*)p; p += FHID * 4;
    float* colsum2 = (float*)p; p += FOUT * 4;

    // xb (bf16 copy of x, 8MB) aliases bufA: dead before k_gemm writes bufA.
    unsigned short* xb = (unsigned short*)bufA;

    hipMemsetAsync(mask, 0, (size_t)NPTS * (NPTS / 32) * 4, stream); // 8 MB
    hipMemsetAsync(Esum, 0, (2 + 2 * NCLU + FHID + FOUT) * sizeof(float), stream);

    k_sumsq<<<NPTS, 256, 0, stream>>>(x, sq);
    k_tobf16<<<(NPTS * FIN / 4) / 256, 256, 0, stream>>>(x, xb);
    k_gram_topk<<<NPTS / GR_ROWS, 256, 0, stream>>>(xb, sq, topidx);
    k_set_edges<<<(NPTS * KNEI + 255) / 256, 256, 0, stream>>>(topidx, mask);
    k_degree<<<NPTS, 64, 0, stream>>>(mask, degf, inv, Esum);

    // layer 1: P = x @ W1 ; h = act1(P*skip1 + A_hat@P + b1)
    k_gemm<<<dim3(FHID / 64, NPTS / 64), 256, 0, stream>>>(x, W1, bufA, NPTS, FIN, FHID);
    k_colsum<<<dim3(FHID / 256, 64), 256, 0, stream>>>(bufA, colsum1, FHID);
    k_aggregate<1><<<NPTS, 256, 0, stream>>>(bufA, bufB, skip1, b1, inv, mask, colsum1, FHID);
    // layer 2: P2 = h @ W2 ; emb = P2*skip2 + A_hat@P2 + b2
    k_gemm<<<dim3(FOUT / 64, NPTS / 64), 256, 0, stream>>>(bufB, W2, bufA, NPTS, FHID, FOUT);
    k_colsum<<<dim3(FOUT / 256, 64), 256, 0, stream>>>(bufA, colsum2, FOUT);
    k_aggregate<0><<<NPTS, 256, 0, stream>>>(bufA, bufB, skip2, b2, inv, mask, colsum2, FOUT);

    k_assign<<<NPTS, 64, 0, stream>>>(bufB, Wt, bt, assign);
    k_colsumA<<<NPTS / 256, 256, 0, stream>>>(assign, colA);
    k_spectral<<<NPTS, 256, 0, stream>>>(mask, assign, degf, colA, T1, vvec);
    k_final<<<1, 1, 0, stream>>>(T1, vvec, Esum, (float*)d_out);
}

// Round 8
// 1150.832 us; speedup vs baseline: 5.2505x; 2.0713x over previous
//
#include <hip/hip_runtime.h>
#include <math.h>
#include <stdint.h>

#define NPTS 8192
#define FIN 512
#define FHID 512
#define FOUT 256
#define NCLU 10
#define KNEI 10
#define GAMMA_F 2.0f
#define LISTCAP 4160   // > 4096 direct cap and > 4095 complement cap

typedef __attribute__((ext_vector_type(4))) float f32x4;
typedef __attribute__((ext_vector_type(8))) short bf16x8;

// ---------------- sum of squares per row ----------------
__global__ void k_sumsq(const float* __restrict__ x, float* __restrict__ sq) {
    int row = blockIdx.x;
    const float* xr = x + (size_t)row * FIN;
    float s = 0.f;
    for (int k = threadIdx.x; k < FIN; k += 256) s += xr[k] * xr[k];
    __shared__ float red[256];
    red[threadIdx.x] = s; __syncthreads();
    for (int off = 128; off > 0; off >>= 1) {
        if (threadIdx.x < off) red[threadIdx.x] += red[threadIdx.x + off];
        __syncthreads();
    }
    if (threadIdx.x == 0) sq[row] = red[0];
}

// ---------------- f32 -> bf16 (RNE) ----------------
__global__ void k_tobf16(const float* __restrict__ x, unsigned short* __restrict__ xb) {
    int i = blockIdx.x * 256 + threadIdx.x;   // one float4 per thread
    f32x4 v = reinterpret_cast<const f32x4*>(x)[i];
    ushort4 o;
    #pragma unroll
    for (int e = 0; e < 4; e++) {
        union { float f; unsigned u; } cvt; cvt.f = v[e];
        unsigned r = (cvt.u + 0x7FFFu + ((cvt.u >> 16) & 1u)) >> 16;
        ((unsigned short*)&o)[e] = (unsigned short)r;
    }
    reinterpret_cast<ushort4*>(xb)[i] = o;
}

// ---------------- fused MFMA gram + exp + per-row top-10 ----------------
#define GR_ROWS 16
#define GR_BN 512
#define GR_TILES (NPTS / GR_BN)   // 16

__global__ __launch_bounds__(256, 2) void k_gram_topk(
    const unsigned short* __restrict__ xb, const float* __restrict__ sq, int* __restrict__ topidx)
{
    __shared__ float Sl[GR_ROWS][GR_BN + 1];
    __shared__ float tval[GR_ROWS][KNEI];
    __shared__ int   tidxs[GR_ROWS][KNEI];

    const int tid  = threadIdx.x;
    const int lane = tid & 63;
    const int wv   = tid >> 6;            // 0..3
    const int r0   = blockIdx.x * GR_ROWS;

    if (tid < GR_ROWS * KNEI) {
        tval[tid / KNEI][tid % KNEI] = -INFINITY;
        tidxs[tid / KNEI][tid % KNEI] = 0x7fffffff;
    }
    __syncthreads();

    const int arow  = r0 + (lane & 15);
    const int akoff = (lane >> 4) * 8;
    bf16x8 afr[16];
    #pragma unroll
    for (int ks = 0; ks < 16; ks++)
        afr[ks] = *reinterpret_cast<const bf16x8*>(xb + (size_t)arow * FIN + ks * 32 + akoff);

    float si_r[4];
    #pragma unroll
    for (int r = 0; r < 4; r++) si_r[r] = sq[r0 + (lane >> 4) * 4 + r];

    for (int t = 0; t < GR_TILES; ++t) {
        const int c0 = t * GR_BN + wv * 128;
        f32x4 acc[8];
        #pragma unroll
        for (int ct = 0; ct < 8; ct++) acc[ct] = (f32x4){0.f, 0.f, 0.f, 0.f};

        #pragma unroll
        for (int ks = 0; ks < 16; ks++) {
            #pragma unroll
            for (int ct = 0; ct < 8; ct++) {
                const int j = c0 + ct * 16 + (lane & 15);
                bf16x8 bfr = *reinterpret_cast<const bf16x8*>(xb + (size_t)j * FIN + ks * 32 + akoff);
                acc[ct] = __builtin_amdgcn_mfma_f32_16x16x32_bf16(afr[ks], bfr, acc[ct], 0, 0, 0);
            }
        }

        #pragma unroll
        for (int ct = 0; ct < 8; ct++) {
            const int col = wv * 128 + ct * 16 + (lane & 15);
            const int gj  = t * GR_BN + col;
            const float sjv = sq[gj];
            #pragma unroll
            for (int r = 0; r < 4; r++) {
                const int row = (lane >> 4) * 4 + r;
                const int gi  = r0 + row;
                const float d2 = si_r[r] + sjv - 2.f * acc[ct][r];
                Sl[row][col] = (gj == gi) ? -INFINITY : expf(-d2 * 0.5f);
            }
        }
        __syncthreads();

        for (int q = 0; q < 4; ++q) {
            int r = wv * 4 + q;
            for (int base = 0; base < GR_BN; base += 64) {
                float v = Sl[r][base + lane];
                int gj = t * GR_BN + base + lane;
                float rv9 = tval[r][KNEI - 1];
                int ri9 = tidxs[r][KNEI - 1];
                unsigned long long bal = __ballot(v > rv9 || (v == rv9 && gj < ri9));
                if (lane == 0 && bal) {
                    while (bal) {
                        int l = __ffsll((unsigned long long)bal) - 1;
                        bal &= bal - 1;
                        float cv = Sl[r][base + l];
                        int cj = t * GR_BN + base + l;
                        float a9 = tval[r][KNEI - 1];
                        int i9 = tidxs[r][KNEI - 1];
                        if (cv > a9 || (cv == a9 && cj < i9)) {
                            int pp = KNEI - 1;
                            tval[r][pp] = cv; tidxs[r][pp] = cj;
                            while (pp > 0) {
                                float pv = tval[r][pp - 1]; int pi = tidxs[r][pp - 1];
                                if (cv > pv || (cv == pv && cj < pi)) {
                                    tval[r][pp] = pv; tidxs[r][pp] = pi;
                                    tval[r][pp - 1] = cv; tidxs[r][pp - 1] = cj;
                                    --pp;
                                } else break;
                            }
                        }
                    }
                }
            }
        }
        __syncthreads();
    }

    if (tid < GR_ROWS * KNEI) {
        int r = tid / KNEI, m = tid % KNEI;
        topidx[(size_t)(r0 + r) * KNEI + m] = tidxs[r][m];
    }
}

// ---------------- build symmetric adjacency bitmask ----------------
__global__ void k_set_edges(const int* __restrict__ topidx, unsigned int* __restrict__ mask) {
    int t = blockIdx.x * 256 + threadIdx.x;
    if (t >= NPTS * KNEI) return;
    int i = t / KNEI;
    int j = topidx[t];
    atomicOr(&mask[(size_t)i * (NPTS / 32) + (j >> 5)], 1u << (j & 31));
    atomicOr(&mask[(size_t)j * (NPTS / 32) + (i >> 5)], 1u << (i & 31));
}

// ---------------- degree, inv ----------------
__global__ void k_degree(const unsigned int* __restrict__ mask, float* __restrict__ degf,
                         float* __restrict__ inv) {
    int i = blockIdx.x, lane = threadIdx.x;  // 64 threads
    int c = 0;
    for (int w = lane; w < NPTS / 32; w += 64) c += __popc(mask[(size_t)i * (NPTS / 32) + w]);
    for (int off = 32; off > 0; off >>= 1) c += __shfl_xor(c, off);
    if (lane == 0) {
        float d = (float)c;
        degf[i] = d;
        inv[i] = (c > 0) ? 1.0f / d : 0.0f;
    }
}

// ---------------- generic f32 GEMM ----------------
__global__ __launch_bounds__(256) void k_gemm(const float* __restrict__ A, const float* __restrict__ B,
                                              float* __restrict__ C, int M, int Kd, int Nd) {
    __shared__ float Al[64][17];
    __shared__ float Bl[16][65];
    int tid = threadIdx.x;
    int bx = blockIdx.x, by = blockIdx.y;
    int tx = tid & 15, ty = tid >> 4;
    float acc[4][4];
    #pragma unroll
    for (int i = 0; i < 4; i++)
        #pragma unroll
        for (int j = 0; j < 4; j++) acc[i][j] = 0.f;

    for (int kt = 0; kt < Kd; kt += 16) {
        #pragma unroll
        for (int l = 0; l < 4; l++) {
            int e = tid + l * 256;
            int r = e >> 4, k = e & 15;
            Al[r][k] = A[(size_t)(by * 64 + r) * Kd + kt + k];
        }
        #pragma unroll
        for (int l = 0; l < 4; l++) {
            int e = tid + l * 256;
            int r = e >> 6, n = e & 63;
            Bl[r][n] = B[(size_t)(kt + r) * Nd + bx * 64 + n];
        }
        __syncthreads();
        #pragma unroll
        for (int k = 0; k < 16; k++) {
            float a[4], b[4];
            #pragma unroll
            for (int i = 0; i < 4; i++) a[i] = Al[ty * 4 + i][k];
            #pragma unroll
            for (int j = 0; j < 4; j++) b[j] = Bl[k][tx * 4 + j];
            #pragma unroll
            for (int i = 0; i < 4; i++)
                #pragma unroll
                for (int j = 0; j < 4; j++) acc[i][j] = fmaf(a[i], b[j], acc[i][j]);
        }
        __syncthreads();
    }
    #pragma unroll
    for (int i = 0; i < 4; i++)
        #pragma unroll
        for (int j = 0; j < 4; j++)
            C[(size_t)(by * 64 + ty * 4 + i) * Nd + bx * 64 + tx * 4 + j] = acc[i][j];
}

// ---------------- column sums of P: colsum[f] = sum_j P[j,f] ----------------
__global__ __launch_bounds__(256) void k_colsum(const float* __restrict__ P, float* __restrict__ colsum, int Fd) {
    int f = blockIdx.x * 256 + threadIdx.x;
    int r0 = blockIdx.y * (NPTS / 64);
    float s = 0.f;
    for (int r = 0; r < NPTS / 64; r++) s += P[(size_t)(r0 + r) * Fd + f];
    atomicAdd(&colsum[f], s);
}

// ---------------- aggregation + skip + bias + activation (dual-mode) ----------------
template <int ACT>
__global__ __launch_bounds__(256) void k_aggregate(const float* __restrict__ P, float* __restrict__ OUT,
        const float* __restrict__ skip, const float* __restrict__ bias,
        const float* __restrict__ inv, const unsigned int* __restrict__ mask,
        const float* __restrict__ colsum, int Fd) {
    __shared__ unsigned short list[LISTCAP];
    __shared__ int cnt_total;
    __shared__ int pos;
    int i = blockIdx.x, tid = threadIdx.x;
    if (tid == 0) { cnt_total = 0; pos = 0; }
    __syncthreads();
    unsigned int w = mask[(size_t)i * (NPTS / 32) + tid];  // 256 words, 256 threads
    atomicAdd(&cnt_total, __popc(w));
    __syncthreads();
    const int deg = cnt_total;
    const bool comp = deg > 4096;
    unsigned int wm = comp ? ~w : w;
    if (comp && tid == (i >> 5)) wm &= ~(1u << (i & 31));   // exclude self from complement
    while (wm) {
        int b = __ffs(wm) - 1;
        wm &= wm - 1;
        int pp = atomicAdd(&pos, 1);
        list[pp] = (unsigned short)(tid * 32 + b);
    }
    __syncthreads();
    const int n = comp ? (NPTS - 1 - deg) : deg;
    const float vinv = inv[i];
    for (int f = tid; f < Fd; f += 256) {
        float s = 0.f;
        for (int q = 0; q < n; q++) s += P[(size_t)list[q] * Fd + f];
        const float pif = P[(size_t)i * Fd + f];
        const float nb = comp ? (colsum[f] - pif - s) : s;
        float o = pif * skip[f] + vinv * nb + bias[f];
        if (ACT == 1) o = (o > 0.f) ? 1.0507009873554805f * o : 0.f;
        OUT[(size_t)i * Fd + f] = o;
    }
}

// ---------------- logits + softmax -> assign ----------------
__global__ void k_assign(const float* __restrict__ emb, const float* __restrict__ Wt,
                         const float* __restrict__ bt, float* __restrict__ assign) {
    int i = blockIdx.x, lane = threadIdx.x;  // 64 threads
    float e[4];
    #pragma unroll
    for (int m = 0; m < 4; m++) e[m] = emb[(size_t)i * FOUT + lane + 64 * m];
    float logit[NCLU];
    #pragma unroll
    for (int c = 0; c < NCLU; c++) {
        float p = 0.f;
        #pragma unroll
        for (int m = 0; m < 4; m++) p = fmaf(e[m], Wt[c * FOUT + lane + 64 * m], p);
        #pragma unroll
        for (int off = 32; off > 0; off >>= 1) p += __shfl_xor(p, off);
        logit[c] = p + bt[c];
    }
    float mx = logit[0];
    #pragma unroll
    for (int c = 1; c < NCLU; c++) mx = fmaxf(mx, logit[c]);
    float sum = 0.f, pr[NCLU];
    #pragma unroll
    for (int c = 0; c < NCLU; c++) { pr[c] = expf(logit[c] - mx); sum += pr[c]; }
    float isum = 1.f / sum;
    if (lane < NCLU) {
        float v = 0.f;
        #pragma unroll
        for (int c = 0; c < NCLU; c++) if (lane == c) v = pr[c];
        assign[(size_t)i * NCLU + lane] = v * isum;
    }
}

// ---------------- stats: colA[c], v[c] = sum_i assign[i,c]*deg[i], Esum = sum deg ----------------
// grid: 32 blocks x 256 threads, one node per thread. colA/vvec/Esum pre-zeroed.
__global__ __launch_bounds__(256) void k_stats(const float* __restrict__ assign,
        const float* __restrict__ degf, float* __restrict__ colA,
        float* __restrict__ vvec, float* __restrict__ Esum) {
    __shared__ float sc[NCLU], sv[NCLU], se;
    int tid = threadIdx.x;
    if (tid < NCLU) { sc[tid] = 0.f; sv[tid] = 0.f; }
    if (tid == 0) se = 0.f;
    __syncthreads();
    int i = blockIdx.x * 256 + tid;
    const float d = degf[i];
    const float* ar = assign + (size_t)i * NCLU;
    float ed = d;
    #pragma unroll
    for (int off = 32; off > 0; off >>= 1) ed += __shfl_xor(ed, off);
    if ((tid & 63) == 0) atomicAdd(&se, ed);
    #pragma unroll
    for (int c = 0; c < NCLU; c++) {
        float a = ar[c];
        float av = a * d;
        #pragma unroll
        for (int off = 32; off > 0; off >>= 1) { a += __shfl_xor(a, off); av += __shfl_xor(av, off); }
        if ((tid & 63) == 0) { atomicAdd(&sc[c], a); atomicAdd(&sv[c], av); }
    }
    __syncthreads();
    if (tid < NCLU) { atomicAdd(&colA[tid], sc[tid]); atomicAdd(&vvec[tid], sv[tid]); }
    if (tid == NCLU) atomicAdd(Esum, se);
}

// ---------------- spectral: Tpart[i] (no atomics) ----------------
__global__ __launch_bounds__(256) void k_spectral(const unsigned int* __restrict__ mask,
        const float* __restrict__ assign, const float* __restrict__ colA,
        float* __restrict__ Tpart) {
    __shared__ unsigned short list[LISTCAP];
    __shared__ int cnt_total;
    __shared__ int pos;
    __shared__ float red[4][NCLU];
    int i = blockIdx.x, tid = threadIdx.x;
    if (tid == 0) { cnt_total = 0; pos = 0; }
    __syncthreads();
    unsigned int w = mask[(size_t)i * (NPTS / 32) + tid];
    atomicAdd(&cnt_total, __popc(w));
    __syncthreads();
    const int deg = cnt_total;
    const bool comp = deg > 4096;
    unsigned int wm = comp ? ~w : w;
    if (comp && tid == (i >> 5)) wm &= ~(1u << (i & 31));
    while (wm) {
        int b = __ffs(wm) - 1;
        wm &= wm - 1;
        int pp = atomicAdd(&pos, 1);
        list[pp] = (unsigned short)(tid * 32 + b);
    }
    __syncthreads();
    const int n = comp ? (NPTS - 1 - deg) : deg;
    float yc[NCLU];
    #pragma unroll
    for (int c = 0; c < NCLU; c++) yc[c] = 0.f;
    for (int q = tid; q < n; q += 256) {
        const float* aj = assign + (size_t)list[q] * NCLU;
        #pragma unroll
        for (int c = 0; c < NCLU; c++) yc[c] += aj[c];
    }
    #pragma unroll
    for (int c = 0; c < NCLU; c++) {
        #pragma unroll
        for (int off = 32; off > 0; off >>= 1) yc[c] += __shfl_xor(yc[c], off);
    }
    int wv = tid >> 6, lane = tid & 63;
    if (lane == 0) {
        #pragma unroll
        for (int c = 0; c < NCLU; c++) red[wv][c] = yc[c];
    }
    __syncthreads();
    if (tid == 0) {
        const float* ai = assign + (size_t)i * NCLU;
        float t = 0.f;
        #pragma unroll
        for (int c = 0; c < NCLU; c++) {
            float y = red[0][c] + red[1][c] + red[2][c] + red[3][c];
            if (comp) y = colA[c] - ai[c] - y;
            t = fmaf(y, ai[c], t);
        }
        Tpart[i] = t;
    }
}

// ---------------- final scalar: reduce Tpart + combine ----------------
__global__ __launch_bounds__(256) void k_final(const float* __restrict__ Tpart,
        const float* __restrict__ v, const float* __restrict__ Esum, float* __restrict__ out) {
    __shared__ float red[256];
    int tid = threadIdx.x;
    float s = 0.f;
    for (int i = tid; i < NPTS; i += 256) s += Tpart[i];
    red[tid] = s; __syncthreads();
    for (int off = 128; off > 0; off >>= 1) {
        if (tid < off) red[tid] += red[tid + off];
        __syncthreads();
    }
    if (tid == 0) {
        float E = *Esum;
        float v2 = 0.f;
        for (int c = 0; c < NCLU; c++) v2 += v[c] * v[c];
        float tr_norm = v2 / (2.f * E);
        out[0] = -(red[0] - tr_norm) / (2.f * E);
    }
}

extern "C" void kernel_launch(void* const* d_in, const int* in_sizes, int n_in,
                              void* d_out, int out_size, void* d_ws, size_t ws_size,
                              hipStream_t stream) {
    const float* x     = (const float*)d_in[0];
    const float* W1    = (const float*)d_in[1];
    const float* b1    = (const float*)d_in[2];
    const float* skip1 = (const float*)d_in[3];
    const float* W2    = (const float*)d_in[4];
    const float* b2    = (const float*)d_in[5];
    const float* skip2 = (const float*)d_in[6];
    const float* Wt    = (const float*)d_in[7];
    const float* bt    = (const float*)d_in[8];

    char* ws = (char*)d_ws;
    float* bufA = (float*)ws;                                   // 16 MB  [N x 512]
    float* bufB = (float*)(ws + ((size_t)16 << 20));            // 16 MB  [N x 512]
    unsigned int* mask = (unsigned int*)(ws + ((size_t)32 << 20)); // 8 MB bitmask
    char* p = ws + ((size_t)40 << 20);
    float* sq     = (float*)p; p += NPTS * 4;
    float* degf   = (float*)p; p += NPTS * 4;
    float* inv    = (float*)p; p += NPTS * 4;
    int*   topidx = (int*)p;   p += (size_t)NPTS * KNEI * 4;
    float* assign = (float*)p; p += (size_t)NPTS * NCLU * 4;
    float* Tpart  = (float*)p; p += NPTS * 4;
    // contiguous zero-region: Esum, vvec[10], colA[10], colsum1[512], colsum2[256]
    float* Esum    = (float*)p; p += 4;
    float* vvec    = (float*)p; p += NCLU * 4;
    float* colA    = (float*)p; p += NCLU * 4;
    float* colsum1 = (float*)p; p += FHID * 4;
    float* colsum2 = (float*)p; p += FOUT * 4;

    // xb (bf16 copy of x, 8MB) aliases bufA: dead before k_gemm writes bufA.
    unsigned short* xb = (unsigned short*)bufA;

    hipMemsetAsync(mask, 0, (size_t)NPTS * (NPTS / 32) * 4, stream); // 8 MB
    hipMemsetAsync(Esum, 0, (1 + 2 * NCLU + FHID + FOUT) * sizeof(float), stream);

    k_sumsq<<<NPTS, 256, 0, stream>>>(x, sq);
    k_tobf16<<<(NPTS * FIN / 4) / 256, 256, 0, stream>>>(x, xb);
    k_gram_topk<<<NPTS / GR_ROWS, 256, 0, stream>>>(xb, sq, topidx);
    k_set_edges<<<(NPTS * KNEI + 255) / 256, 256, 0, stream>>>(topidx, mask);
    k_degree<<<NPTS, 64, 0, stream>>>(mask, degf, inv);

    // layer 1: P = x @ W1 ; h = act1(P*skip1 + A_hat@P + b1)
    k_gemm<<<dim3(FHID / 64, NPTS / 64), 256, 0, stream>>>(x, W1, bufA, NPTS, FIN, FHID);
    k_colsum<<<dim3(FHID / 256, 64), 256, 0, stream>>>(bufA, colsum1, FHID);
    k_aggregate<1><<<NPTS, 256, 0, stream>>>(bufA, bufB, skip1, b1, inv, mask, colsum1, FHID);
    // layer 2: P2 = h @ W2 ; emb = P2*skip2 + A_hat@P2 + b2
    k_gemm<<<dim3(FOUT / 64, NPTS / 64), 256, 0, stream>>>(bufB, W2, bufA, NPTS, FHID, FOUT);
    k_colsum<<<dim3(FOUT / 256, 64), 256, 0, stream>>>(bufA, colsum2, FOUT);
    k_aggregate<0><<<NPTS, 256, 0, stream>>>(bufA, bufB, skip2, b2, inv, mask, colsum2, FOUT);

    k_assign<<<NPTS, 64, 0, stream>>>(bufB, Wt, bt, assign);
    k_stats<<<NPTS / 256, 256, 0, stream>>>(assign, degf, colA, vvec, Esum);
    k_spectral<<<NPTS, 256, 0, stream>>>(mask, assign, colA, Tpart);
    k_final<<<1, 256, 0, stream>>>(Tpart, vvec, Esum, (float*)d_out);
}